// Round 6
// baseline (232.112 us; speedup 1.0000x reference)
//
#include <hip/hip_runtime.h>
#include <hip/hip_fp16.h>

#define ND 100000   // N_NODES
#define NE 50000    // N_EDGES
#define AR 32       // EDGE_ARITY
#define DG 16       // NODE_DEG
#define D  128      // D_IN == D_OUT == TV

typedef _Float16 half8_t __attribute__((ext_vector_type(8)));
typedef _Float16 half4_t __attribute__((ext_vector_type(4)));
typedef float    f32x4_t __attribute__((ext_vector_type(4)));

#define APAD 136   // LDS A-row stride (halves): 16B-aligned, 2-way aliasing free

// ---------------------------------------------------------------------------
// K0: fused prep.  blocks 0..63: w1,w2 -> fragment-major fp16.
//     block 64: inter_nw = mean(cos(w3 rows, w3[0])).
// Fragment-major: o = ((ntile*4 + ktile)*64 + lane)*8 + j
//   <-> B[k = ktile*32 + (lane>>4)*8 + j][n = ntile*16 + (lane&15)]
// ---------------------------------------------------------------------------
__global__ __launch_bounds__(256) void k_prep(const float* __restrict__ w1,
                                              const float* __restrict__ w2,
                                              const float* __restrict__ w3,
                                              _Float16* __restrict__ w1f,
                                              _Float16* __restrict__ w2f,
                                              float* __restrict__ inter_out) {
    if (blockIdx.x == 64) {
        __shared__ float red[128];
        int j = threadIdx.x;
        if (j < 128) {
            float dot = 0.f, sq = 0.f, sq0 = 0.f;
            #pragma unroll 8
            for (int k = 0; k < D; ++k) {
                float wj = w3[j * D + k];
                float w0 = w3[k];
                dot += wj * w0;
                sq  += wj * wj;
                sq0 += w0 * w0;
            }
            red[j] = dot / (sqrtf(sq0) * sqrtf(sq));
        }
        __syncthreads();
        if (j == 0) {
            float s = 0.f;
            for (int i = 0; i < 128; ++i) s += red[i];
            inter_out[0] = s / 128.f;
        }
        return;
    }
    int o = blockIdx.x * 256 + threadIdx.x;   // 0..16383
    int j    = o & 7;
    int lane = (o >> 3) & 63;
    int frag = o >> 9;                        // 0..31
    int ntile = frag >> 2, ktile = frag & 3;
    int n = ntile * 16 + (lane & 15);
    int k = ktile * 32 + (lane >> 4) * 8 + j;
    w1f[o] = (_Float16)w1[k * D + n];
    w2f[o] = (_Float16)w2[k * D + n];
}

// ---------------------------------------------------------------------------
// K1: xw = (x @ w1) * inter_nw via MFMA -> row-major fp16 table.
// TRANSPOSED-OPERAND trick: mfma(wfrag, xfrag, acc) computes (X*W)^T tile,
// so lane l15 = output ROW, reg i = 4 consecutive output COLS at
// nt*16 + quad*4 -> contiguous 8 B half4 stores (no LDS bounce, no 2B stores).
// ---------------------------------------------------------------------------
__global__ __launch_bounds__(256) void k_xw(const float* __restrict__ x,
                                            const _Float16* __restrict__ w1f_g,
                                            const float* __restrict__ inter_p,
                                            _Float16* __restrict__ xwh) {
    __shared__ _Float16 wfrag[D * D];     // 32 KB, fragment-major
    __shared__ _Float16 xs[64 * APAD];    // 17 KB
    int t = threadIdx.x;
    {
        const float4* src = (const float4*)w1f_g;
        float4* dst = (float4*)wfrag;
        #pragma unroll
        for (int i = 0; i < 8; ++i) dst[i * 256 + t] = src[i * 256 + t];
    }
    int rowbase = blockIdx.x * 64;
    #pragma unroll
    for (int p = 0; p < 8; ++p) {
        int idx = p * 1024 + t * 4;
        int r = idx >> 7, c = idx & 127;
        int grow = rowbase + r;
        float4 v = make_float4(0.f, 0.f, 0.f, 0.f);
        if (grow < ND) v = ((const float4*)x)[(size_t)grow * 32 + (c >> 2)];
        half4_t h = { (_Float16)v.x, (_Float16)v.y, (_Float16)v.z, (_Float16)v.w };
        *(half4_t*)&xs[r * APAD + c] = h;
    }
    __syncthreads();

    int wave = t >> 6, lane = t & 63;
    int quad = lane >> 4, l15 = lane & 15;
    int m0 = wave * 16;
    float inter = inter_p[0];

    half8_t a[4];   // X fragment: [n=l15 (row), k=quad*8+j] — valid as B-operand
    #pragma unroll
    for (int kt = 0; kt < 4; ++kt)
        a[kt] = *(const half8_t*)&xs[(m0 + l15) * APAD + kt * 32 + quad * 8];

    int grow = rowbase + m0 + l15;          // this lane's output row
    #pragma unroll
    for (int nt = 0; nt < 8; ++nt) {
        f32x4_t acc = {0.f, 0.f, 0.f, 0.f};
        #pragma unroll
        for (int kt = 0; kt < 4; ++kt) {
            half8_t b = *(const half8_t*)&wfrag[((nt * 4 + kt) * 64 + lane) * 8];
            // swapped: A=W-frag (A[m=n][k]=W[k][n]), B=X-frag -> D=(X*W)^T
            acc = __builtin_amdgcn_mfma_f32_16x16x32_f16(b, a[kt], acc, 0, 0, 0);
        }
        half4_t hv = { (_Float16)(acc[0] * inter), (_Float16)(acc[1] * inter),
                       (_Float16)(acc[2] * inter), (_Float16)(acc[3] * inter) };
        if (grow < ND)
            *(half4_t*)(xwh + (size_t)grow * D + nt * 16 + quad * 4) = hv;
    }
}

// ---------------------------------------------------------------------------
// K2a: edge gather, max memory-level parallelism.
// 16 lanes/edge, 4 edges/wave, 16 edges/block. No LDS, no sort.
// Two hunks of 16 explicitly-staged half8 loads -> ~16 outstanding/wave.
// ---------------------------------------------------------------------------
__global__ __launch_bounds__(256) void k_gather_e(const int* __restrict__ seq,
                                                  const _Float16* __restrict__ xwh,
                                                  _Float16* __restrict__ ea) {
    int t = threadIdx.x;
    int wave = t >> 6, lane = t & 63;
    int e = lane >> 4, l16 = lane & 15;
    int le = wave * 4 + e;
    int eg = blockIdx.x * 16 + le;           // 3125*16 == 50000 exact
    int base = e * 16;

    int sv0 = seq[(size_t)eg * AR + l16];         // slots 0..15
    int sv1 = seq[(size_t)eg * AR + 16 + l16];    // slots 16..31
    unsigned long long b0 = __ballot(sv0 > 0);
    unsigned long long b1 = __ballot(sv1 > 0);
    unsigned int f0 = (unsigned int)(b0 >> base) & 0xFFFFu;
    unsigned int f1 = (unsigned int)(b1 >> base) & 0xFFFFu;
    int cnt = __popc(f0) + __popc(f1);
    bool allv = (cnt == 0);
    if (allv) cnt = AR;
    float wv = 1.f / (float)cnt;

    float acc[8] = {};
    int colOff = l16 * 8;
    #pragma unroll
    for (int h = 0; h < 2; ++h) {
        int sreg = h ? sv1 : sv0;
        float w[16];
        const _Float16* addr[16];
        #pragma unroll
        for (int u = 0; u < 16; ++u) {
            int rr = __shfl(sreg, base + u, 64);
            w[u] = ((rr > 0) | allv) ? wv : 0.f;
            addr[u] = xwh + (size_t)rr * D + colOff;
        }
        half8_t v[16];
        #pragma unroll
        for (int u = 0; u < 16; ++u) v[u] = *(const half8_t*)addr[u];
        #pragma unroll
        for (int u = 0; u < 16; ++u) {
            #pragma unroll
            for (int jj = 0; jj < 8; ++jj)
                acc[jj] = fmaf(w[u], (float)v[u][jj], acc[jj]);
        }
    }
    half8_t hv;
    #pragma unroll
    for (int jj = 0; jj < 8; ++jj) hv[jj] = (_Float16)fmaxf(acc[jj], 0.f);
    *(half8_t*)(ea + (size_t)eg * D + colOff) = hv;
}

// ---------------------------------------------------------------------------
// K2b: e1 = ea @ w2 via MFMA, transposed-operand epilogue (half4 stores).
// ---------------------------------------------------------------------------
__global__ __launch_bounds__(256) void k_gemm_e(const _Float16* __restrict__ ea,
                                                const _Float16* __restrict__ w2f_g,
                                                _Float16* __restrict__ e1h) {
    __shared__ _Float16 wfrag[D * D];
    __shared__ _Float16 et[64 * APAD];
    int t = threadIdx.x;
    {
        const float4* src = (const float4*)w2f_g;
        float4* dst = (float4*)wfrag;
        #pragma unroll
        for (int i = 0; i < 8; ++i) dst[i * 256 + t] = src[i * 256 + t];
    }
    int rowbase = blockIdx.x * 64;
    #pragma unroll
    for (int p = 0; p < 4; ++p) {
        int hidx = p * 2048 + t * 8;
        int r = hidx >> 7, c = hidx & 127;
        int grow = rowbase + r;
        int gs = (grow < NE) ? grow : (NE - 1);
        half8_t v = *(const half8_t*)(ea + (size_t)gs * D + c);
        *(half8_t*)&et[r * APAD + c] = v;
    }
    __syncthreads();

    int wave = t >> 6, lane = t & 63;
    int quad = lane >> 4, l15 = lane & 15;
    int m0 = wave * 16;

    half8_t a[4];
    #pragma unroll
    for (int kt = 0; kt < 4; ++kt)
        a[kt] = *(const half8_t*)&et[(m0 + l15) * APAD + kt * 32 + quad * 8];

    int grow = rowbase + m0 + l15;
    #pragma unroll
    for (int nt = 0; nt < 8; ++nt) {
        f32x4_t acc = {0.f, 0.f, 0.f, 0.f};
        #pragma unroll
        for (int kt = 0; kt < 4; ++kt) {
            half8_t b = *(const half8_t*)&wfrag[((nt * 4 + kt) * 64 + lane) * 8];
            acc = __builtin_amdgcn_mfma_f32_16x16x32_f16(b, a[kt], acc, 0, 0, 0);
        }
        half4_t hv = { (_Float16)acc[0], (_Float16)acc[1],
                       (_Float16)acc[2], (_Float16)acc[3] };
        if (grow < NE)
            *(half4_t*)(e1h + (size_t)grow * D + nt * 16 + quad * 4) = hv;
    }
}

// ---------------------------------------------------------------------------
// K3: node gather, max MLP. 16 lanes/node, 4 nodes/wave, 16 nodes/block.
// All 16 slot-loads staged in registers -> 16 outstanding/wave. f32 out (NT).
// ---------------------------------------------------------------------------
__global__ __launch_bounds__(256) void k_gather_n(const int* __restrict__ useq,
                                                  const _Float16* __restrict__ e1h,
                                                  float* __restrict__ out) {
    int t = threadIdx.x;
    int wave = t >> 6, lane = t & 63;
    int nd = lane >> 4, l16 = lane & 15;
    int ln = wave * 4 + nd;
    int ng = blockIdx.x * 16 + ln;           // 6250*16 == 100000 exact
    int base = nd * 16;

    int sval = useq[(size_t)ng * DG + l16];
    unsigned long long b = __ballot(sval > 0);
    unsigned int f = (unsigned int)(b >> base) & 0xFFFFu;
    int cnt = __popc(f);
    bool allv = (cnt == 0);
    if (allv) cnt = DG;
    float wv = 1.f / (float)cnt;

    int colOff = l16 * 8;
    float w[16];
    const _Float16* addr[16];
    #pragma unroll
    for (int u = 0; u < 16; ++u) {
        int rr = __shfl(sval, base + u, 64);
        w[u] = ((rr > 0) | allv) ? wv : 0.f;
        addr[u] = e1h + (size_t)rr * D + colOff;
    }
    half8_t v[16];
    #pragma unroll
    for (int u = 0; u < 16; ++u) v[u] = *(const half8_t*)addr[u];

    float acc[8] = {};
    #pragma unroll
    for (int u = 0; u < 16; ++u) {
        #pragma unroll
        for (int jj = 0; jj < 8; ++jj)
            acc[jj] = fmaf(w[u], (float)v[u][jj], acc[jj]);
    }
    f32x4_t o0 = { acc[0], acc[1], acc[2], acc[3] };
    f32x4_t o1 = { acc[4], acc[5], acc[6], acc[7] };
    f32x4_t* p = (f32x4_t*)(out + (size_t)ng * D + colOff);
    __builtin_nontemporal_store(o0, p);
    __builtin_nontemporal_store(o1, p + 1);
}

// ---------------------------------------------------------------------------
extern "C" void kernel_launch(void* const* d_in, const int* in_sizes, int n_in,
                              void* d_out, int out_size, void* d_ws, size_t ws_size,
                              hipStream_t stream) {
    const float* x    = (const float*)d_in[0];
    const int*   seq  = (const int*)d_in[1];
    const int*   useq = (const int*)d_in[2];
    // d_in[3] = TextVector: unused (reference overwrites it with weight3[0])
    const float* w1   = (const float*)d_in[4];
    const float* w2   = (const float*)d_in[5];
    const float* w3   = (const float*)d_in[6];
    float* out = (float*)d_out;

    // Scratch: d_out hosts xwh [0,25.6M) and ea [25.6M,38.4M) (both dead
    // before k_gather_n overwrites d_out with the f32 output).
    // d_ws: inter scalar | w1frag 32KB | w2frag 32KB | e1h 12.8MB.
    _Float16* xwh   = (_Float16*)d_out;
    _Float16* ea    = (_Float16*)d_out + (size_t)ND * D;
    float*    inter = (float*)d_ws;
    _Float16* w1f   = (_Float16*)((char*)d_ws + 256);
    _Float16* w2f   = (_Float16*)((char*)d_ws + 256 + 32768);
    _Float16* e1h   = (_Float16*)((char*)d_ws + 256 + 65536);

    hipLaunchKernelGGL(k_prep,     dim3(65),             dim3(256), 0, stream, w1, w2, w3, w1f, w2f, inter);
    hipLaunchKernelGGL(k_xw,       dim3((ND + 63) / 64), dim3(256), 0, stream, x, w1f, inter, xwh);
    hipLaunchKernelGGL(k_gather_e, dim3(NE / 16),        dim3(256), 0, stream, seq, xwh, ea);
    hipLaunchKernelGGL(k_gemm_e,   dim3((NE + 63) / 64), dim3(256), 0, stream, ea, w2f, e1h);
    hipLaunchKernelGGL(k_gather_n, dim3(ND / 16),        dim3(256), 0, stream, useq, e1h, out);
}

// Round 8
// 227.524 us; speedup vs baseline: 1.0202x; 1.0202x over previous
//
#include <hip/hip_runtime.h>
#include <hip/hip_fp16.h>

#define ND 100000   // N_NODES
#define NE 50000    // N_EDGES
#define AR 32       // EDGE_ARITY
#define DG 16       // NODE_DEG
#define D  128      // D_IN == D_OUT == TV

typedef _Float16 half8_t __attribute__((ext_vector_type(8)));
typedef _Float16 half4_t __attribute__((ext_vector_type(4)));
typedef float    f32x4_t __attribute__((ext_vector_type(4)));

#define APAD 136   // LDS A-row stride (halves): 16B-aligned, 2-way aliasing free
#define EPB 128    // edges per k_gather_e block (256 thr = 128 edges x 2 chunks)

// ---------------------------------------------------------------------------
// K0: fused prep.  blocks 0..63: w1,w2 -> fragment-major fp16.
//     block 64: inter_nw = mean(cos(w3 rows, w3[0])).
// ---------------------------------------------------------------------------
__global__ __launch_bounds__(256) void k_prep(const float* __restrict__ w1,
                                              const float* __restrict__ w2,
                                              const float* __restrict__ w3,
                                              _Float16* __restrict__ w1f,
                                              _Float16* __restrict__ w2f,
                                              float* __restrict__ inter_out) {
    if (blockIdx.x == 64) {
        __shared__ float red[128];
        int j = threadIdx.x;
        if (j < 128) {
            float dot = 0.f, sq = 0.f, sq0 = 0.f;
            #pragma unroll 8
            for (int k = 0; k < D; ++k) {
                float wj = w3[j * D + k];
                float w0 = w3[k];
                dot += wj * w0;
                sq  += wj * wj;
                sq0 += w0 * w0;
            }
            red[j] = dot / (sqrtf(sq0) * sqrtf(sq));
        }
        __syncthreads();
        if (j == 0) {
            float s = 0.f;
            for (int i = 0; i < 128; ++i) s += red[i];
            inter_out[0] = s / 128.f;
        }
        return;
    }
    int o = blockIdx.x * 256 + threadIdx.x;   // 0..16383
    int j    = o & 7;
    int lane = (o >> 3) & 63;
    int frag = o >> 9;                        // 0..31
    int ntile = frag >> 2, ktile = frag & 3;
    int n = ntile * 16 + (lane & 15);
    int k = ktile * 32 + (lane >> 4) * 8 + j;
    w1f[o] = (_Float16)w1[k * D + n];
    w2f[o] = (_Float16)w2[k * D + n];
}

// ---------------------------------------------------------------------------
// K1: xw = (x @ w1) * inter_nw via MFMA (transposed-operand epilogue).
// Output layout: SLICE-MAJOR xws[8][ND][16] halfs (32 B rows per slice) so
// each gather_e block touches only one 3.2 MB slice (per-XCD L2-resident).
// ---------------------------------------------------------------------------
__global__ __launch_bounds__(256) void k_xw(const float* __restrict__ x,
                                            const _Float16* __restrict__ w1f_g,
                                            const float* __restrict__ inter_p,
                                            _Float16* __restrict__ xws) {
    __shared__ _Float16 wfrag[D * D];     // 32 KB, fragment-major
    __shared__ _Float16 xs[64 * APAD];    // 17 KB
    int t = threadIdx.x;
    {
        const float4* src = (const float4*)w1f_g;
        float4* dst = (float4*)wfrag;
        #pragma unroll
        for (int i = 0; i < 8; ++i) dst[i * 256 + t] = src[i * 256 + t];
    }
    int rowbase = blockIdx.x * 64;
    #pragma unroll
    for (int p = 0; p < 8; ++p) {
        int idx = p * 1024 + t * 4;
        int r = idx >> 7, c = idx & 127;
        int grow = rowbase + r;
        float4 v = make_float4(0.f, 0.f, 0.f, 0.f);
        if (grow < ND) v = ((const float4*)x)[(size_t)grow * 32 + (c >> 2)];
        half4_t h = { (_Float16)v.x, (_Float16)v.y, (_Float16)v.z, (_Float16)v.w };
        *(half4_t*)&xs[r * APAD + c] = h;
    }
    __syncthreads();

    int wave = t >> 6, lane = t & 63;
    int quad = lane >> 4, l15 = lane & 15;
    int m0 = wave * 16;
    float inter = inter_p[0];

    half8_t a[4];
    #pragma unroll
    for (int kt = 0; kt < 4; ++kt)
        a[kt] = *(const half8_t*)&xs[(m0 + l15) * APAD + kt * 32 + quad * 8];

    int grow = rowbase + m0 + l15;
    #pragma unroll
    for (int nt = 0; nt < 8; ++nt) {
        f32x4_t acc = {0.f, 0.f, 0.f, 0.f};
        #pragma unroll
        for (int kt = 0; kt < 4; ++kt) {
            half8_t b = *(const half8_t*)&wfrag[((nt * 4 + kt) * 64 + lane) * 8];
            acc = __builtin_amdgcn_mfma_f32_16x16x32_f16(b, a[kt], acc, 0, 0, 0);
        }
        half4_t hv = { (_Float16)(acc[0] * inter), (_Float16)(acc[1] * inter),
                       (_Float16)(acc[2] * inter), (_Float16)(acc[3] * inter) };
        if (grow < ND)   // slice nt, row grow, cols quad*4..+4
            *(half4_t*)(xws + ((size_t)nt * ND + grow) * 16 + quad * 4) = hv;
    }
}

// ---------------------------------------------------------------------------
// K2a: edge gather, XCD-pinned slice s = blockIdx&7.
// 128 edges/block: 256 threads = 128 edges x 2 16-B chunks (exact mapping).
// Phase 1: e = t>>1 reads 16 slots (part = t&1), counts + (idx,weight) -> LDS.
// Phase 2: e2 = t>>1, chunk = t&1; loop all 32 slots, half8 loads from the
// pinned 3.2 MB slice.
// ---------------------------------------------------------------------------
__global__ __launch_bounds__(256) void k_gather_e(const int* __restrict__ seq,
                                                  const _Float16* __restrict__ xws,
                                                  _Float16* __restrict__ ea) {
    __shared__ int2 iw[EPB * AR];   // 32 KB: {row, weight-bits} per slot
    __shared__ int  cpart[256];     // 1 KB
    int t = threadIdx.x;
    int s = blockIdx.x & 7;
    int g = blockIdx.x >> 3;
    int eg0 = g * EPB;

    int e = t >> 1, part = t & 1;                 // edge 0..127, slot-half 0..1
    int egs = min(eg0 + e, NE - 1);
    const int4* sp = (const int4*)(seq + (size_t)egs * AR + part * 16);
    int4 a = sp[0], b = sp[1], c = sp[2], d = sp[3];
    int idxs[16] = { a.x, a.y, a.z, a.w, b.x, b.y, b.z, b.w,
                     c.x, c.y, c.z, c.w, d.x, d.y, d.z, d.w };
    int pc = 0;
    #pragma unroll
    for (int j = 0; j < 16; ++j) pc += (idxs[j] > 0);
    cpart[t] = pc;
    __syncthreads();
    int cnt = cpart[e * 2] + cpart[e * 2 + 1];
    bool allv = (cnt == 0);
    float wv = 1.f / (float)(allv ? AR : cnt);
    #pragma unroll
    for (int j = 0; j < 16; ++j) {
        float w = (allv | (idxs[j] > 0)) ? wv : 0.f;
        iw[e * AR + part * 16 + j] = make_int2(idxs[j], __float_as_int(w));
    }
    __syncthreads();

    int e2 = t >> 1;                              // 0..127
    int chunk = t & 1;                            // which 16 B of the 32 B row
    const _Float16* tab = xws + (size_t)s * ND * 16;

    float acc[8] = {};
    #pragma unroll
    for (int tt = 0; tt < AR; ++tt) {
        int2 p = iw[e2 * AR + tt];
        float w = __int_as_float(p.y);
        half8_t v = *(const half8_t*)(tab + (size_t)p.x * 16 + chunk * 8);
        #pragma unroll
        for (int jj = 0; jj < 8; ++jj)
            acc[jj] = fmaf(w, (float)v[jj], acc[jj]);
    }
    int eg = eg0 + e2;
    if (eg < NE) {
        half8_t h;
        #pragma unroll
        for (int jj = 0; jj < 8; ++jj) h[jj] = (_Float16)fmaxf(acc[jj], 0.f);
        *(half8_t*)(ea + (size_t)eg * D + s * 16 + chunk * 8) = h;
    }
}

// ---------------------------------------------------------------------------
// K2b: e1 = ea @ w2 via MFMA; output SLICE-MAJOR e1s[4][NE][32] halfs
// (64 B rows per slice, 3.2 MB/slice) for the sliced node gather.
// ---------------------------------------------------------------------------
__global__ __launch_bounds__(256) void k_gemm_e(const _Float16* __restrict__ ea,
                                                const _Float16* __restrict__ w2f_g,
                                                _Float16* __restrict__ e1s) {
    __shared__ _Float16 wfrag[D * D];
    __shared__ _Float16 et[64 * APAD];
    int t = threadIdx.x;
    {
        const float4* src = (const float4*)w2f_g;
        float4* dst = (float4*)wfrag;
        #pragma unroll
        for (int i = 0; i < 8; ++i) dst[i * 256 + t] = src[i * 256 + t];
    }
    int rowbase = blockIdx.x * 64;
    #pragma unroll
    for (int p = 0; p < 4; ++p) {
        int hidx = p * 2048 + t * 8;
        int r = hidx >> 7, c = hidx & 127;
        int grow = rowbase + r;
        int gs = (grow < NE) ? grow : (NE - 1);
        half8_t v = *(const half8_t*)(ea + (size_t)gs * D + c);
        *(half8_t*)&et[r * APAD + c] = v;
    }
    __syncthreads();

    int wave = t >> 6, lane = t & 63;
    int quad = lane >> 4, l15 = lane & 15;
    int m0 = wave * 16;

    half8_t a[4];
    #pragma unroll
    for (int kt = 0; kt < 4; ++kt)
        a[kt] = *(const half8_t*)&et[(m0 + l15) * APAD + kt * 32 + quad * 8];

    int grow = rowbase + m0 + l15;
    #pragma unroll
    for (int nt = 0; nt < 8; ++nt) {
        f32x4_t acc = {0.f, 0.f, 0.f, 0.f};
        #pragma unroll
        for (int kt = 0; kt < 4; ++kt) {
            half8_t b = *(const half8_t*)&wfrag[((nt * 4 + kt) * 64 + lane) * 8];
            acc = __builtin_amdgcn_mfma_f32_16x16x32_f16(b, a[kt], acc, 0, 0, 0);
        }
        half4_t hv = { (_Float16)acc[0], (_Float16)acc[1],
                       (_Float16)acc[2], (_Float16)acc[3] };
        if (grow < NE)   // slice nt>>1, col-in-slice (nt&1)*16 + quad*4
            *(half4_t*)(e1s + ((size_t)(nt >> 1) * NE + grow) * 32
                            + (nt & 1) * 16 + quad * 4) = hv;
    }
}

// ---------------------------------------------------------------------------
// K3: node gather, XCD-pinned slice s = blockIdx&3 (each slice cached on 2
// XCDs, 3.2 MB < 4 MB L2). Block: 64 nodes; lane owns (node, 16B-chunk of the
// 64 B slice row), loops all 16 slots.
// ---------------------------------------------------------------------------
__global__ __launch_bounds__(256) void k_gather_n(const int* __restrict__ useq,
                                                  const _Float16* __restrict__ e1s,
                                                  float* __restrict__ out) {
    __shared__ int2 iw[64 * DG];    // 8 KB
    __shared__ int  cpart[256];
    int t = threadIdx.x;
    int s = blockIdx.x & 3;
    int g = blockIdx.x >> 2;
    int ng0 = g * 64;

    int n = t >> 2, part = t & 3;                 // node-in-block, slot-quarter
    int ns = min(ng0 + n, ND - 1);
    int4 a = *(const int4*)(useq + (size_t)ns * DG + part * 4);
    cpart[t] = (a.x > 0) + (a.y > 0) + (a.z > 0) + (a.w > 0);
    __syncthreads();
    int cnt = cpart[n * 4] + cpart[n * 4 + 1] + cpart[n * 4 + 2] + cpart[n * 4 + 3];
    bool allv = (cnt == 0);
    float wv = 1.f / (float)(allv ? DG : cnt);
    int idxs[4] = { a.x, a.y, a.z, a.w };
    #pragma unroll
    for (int j = 0; j < 4; ++j) {
        float w = (allv | (idxs[j] > 0)) ? wv : 0.f;
        iw[n * DG + part * 4 + j] = make_int2(idxs[j], __float_as_int(w));
    }
    __syncthreads();

    int wave = t >> 6, lane = t & 63;
    int n2 = wave * 16 + (lane >> 2);             // 16 nodes per wave, 0..63
    int chunk = lane & 3;                         // which 16 B of the 64 B row
    const _Float16* tab = e1s + (size_t)s * NE * 32;

    float acc[8] = {};
    #pragma unroll
    for (int tt = 0; tt < DG; ++tt) {
        int2 p = iw[n2 * DG + tt];
        float w = __int_as_float(p.y);
        half8_t v = *(const half8_t*)(tab + (size_t)p.x * 32 + chunk * 8);
        #pragma unroll
        for (int jj = 0; jj < 8; ++jj)
            acc[jj] = fmaf(w, (float)v[jj], acc[jj]);
    }
    int ng = ng0 + n2;
    if (ng < ND) {
        f32x4_t o0 = { acc[0], acc[1], acc[2], acc[3] };
        f32x4_t o1 = { acc[4], acc[5], acc[6], acc[7] };
        f32x4_t* p = (f32x4_t*)(out + (size_t)ng * D + s * 32 + chunk * 8);
        __builtin_nontemporal_store(o0, p);
        __builtin_nontemporal_store(o1, p + 1);
    }
}

// ---------------------------------------------------------------------------
extern "C" void kernel_launch(void* const* d_in, const int* in_sizes, int n_in,
                              void* d_out, int out_size, void* d_ws, size_t ws_size,
                              hipStream_t stream) {
    const float* x    = (const float*)d_in[0];
    const int*   seq  = (const int*)d_in[1];
    const int*   useq = (const int*)d_in[2];
    // d_in[3] = TextVector: unused (reference overwrites it with weight3[0])
    const float* w1   = (const float*)d_in[4];
    const float* w2   = (const float*)d_in[5];
    const float* w3   = (const float*)d_in[6];
    float* out = (float*)d_out;

    // Scratch: d_out hosts xws [0,25.6M) and ea [25.6M,38.4M) (dead before
    // k_gather_n overwrites d_out). d_ws: inter | w1f 32K | w2f 32K | e1s 12.8M.
    _Float16* xws   = (_Float16*)d_out;
    _Float16* ea    = (_Float16*)d_out + (size_t)ND * D;
    float*    inter = (float*)d_ws;
    _Float16* w1f   = (_Float16*)((char*)d_ws + 256);
    _Float16* w2f   = (_Float16*)((char*)d_ws + 256 + 32768);
    _Float16* e1s   = (_Float16*)((char*)d_ws + 256 + 65536);

    int eg_grp = (NE + EPB - 1) / EPB;   // 391
    int ng_grp = (ND + 63) / 64;         // 1563

    hipLaunchKernelGGL(k_prep,     dim3(65),             dim3(256), 0, stream, w1, w2, w3, w1f, w2f, inter);
    hipLaunchKernelGGL(k_xw,       dim3((ND + 63) / 64), dim3(256), 0, stream, x, w1f, inter, xws);
    hipLaunchKernelGGL(k_gather_e, dim3(eg_grp * 8),     dim3(256), 0, stream, seq, xws, ea);
    hipLaunchKernelGGL(k_gemm_e,   dim3((NE + 63) / 64), dim3(256), 0, stream, ea, w2f, e1s);
    hipLaunchKernelGGL(k_gather_n, dim3(ng_grp * 4),     dim3(256), 0, stream, useq, e1s, out);
}